// Round 3
// baseline (221.123 us; speedup 1.0000x reference)
//
#include <hip/hip_runtime.h>
#include <hip/hip_bf16.h>

// Masked SDPA, flash-attention + KV-split (flash-decoding style).
// BZ=8, QL=KL=2048, D=128.
// Main kernel: grid = BZ*16*S blocks, 256 thr = 4 waves. Each block: 128 q-rows
// x KV chunk of KLEN/S keys. Wave owns 32 q-rows (two 16-row m-tiles) so each
// K/V B-frag ds_read feeds 2 MFMAs. Partials (unnormalized O', m, l in log2
// units) go to d_ws; fattn_merge combines. Falls back to the proven R2
// single-pass kernel if ws_size is too small.

#define BZ 8
#define QL 2048
#define KLEN 2048
#define DH 128
#define KT 64
#define TOTROWS (BZ * QL)  // 16384

#define KPITCH 136  // bf16 elems; 272B rows -> 2-way bank aliasing (free)
#define VPITCH 72
#define PPITCH 72

typedef float f32x4 __attribute__((ext_vector_type(4)));
typedef __bf16 bf16x8 __attribute__((ext_vector_type(8)));
typedef __bf16 bf16x4 __attribute__((ext_vector_type(4)));
typedef __bf16 bf16x2 __attribute__((ext_vector_type(2)));

// SCALE * log2(e): scores exit QK^T in log2 units; softmax uses exp2.
#define QSC 0.12751879523298232f
#define NEGV -1000000000.0f

// ---------------------------------------------------------------------------
// Split main kernel: 4 waves x 32 q-rows, KV chunk = KLEN/S.
// ---------------------------------------------------------------------------
__global__ __launch_bounds__(256, 2) void fattn_split(
    const float* __restrict__ qg, const float* __restrict__ kg,
    const float* __restrict__ vg, const int* __restrict__ maskg,
    float* __restrict__ opart, float* __restrict__ mlout, int S) {
  __shared__ __bf16 sK[KT][KPITCH];    // 17408 B
  __shared__ __bf16 sVT[DH][VPITCH];   // 18432 B
  __shared__ __bf16 sP[4][32][PPITCH]; // 18432 B  (per-wave, no barrier)

  const int tid = threadIdx.x;
  const int wv = tid >> 6;
  const int ln = tid & 63;
  const int qd = ln >> 4;
  const int lc = ln & 15;

  const int bid = blockIdx.x;
  const int qidx = bid & 15;
  const int t1 = bid >> 4;
  const int s = t1 % S;
  const int b = t1 / S;
  const int qbase = qidx * 128 + wv * 32;  // q-row base (within batch) for this wave

  const int CHUNK = KLEN / S;
  const int NT = CHUNK / KT;

  // ---- Q fragments: 2 m-tiles, A-layout A[m=lane&15][k=quad*8+j], pre-scaled
  bf16x8 qf[2][4];
#pragma unroll
  for (int mt = 0; mt < 2; ++mt) {
    const float* qr = qg + ((size_t)(b * QL + qbase + mt * 16 + lc)) * DH + qd * 8;
#pragma unroll
    for (int kf = 0; kf < 4; ++kf) {
      f32x4 a = *(const f32x4*)(qr + kf * 32);
      f32x4 c = *(const f32x4*)(qr + kf * 32 + 4);
      bf16x8 t;
      t[0] = (__bf16)(a[0] * QSC); t[1] = (__bf16)(a[1] * QSC);
      t[2] = (__bf16)(a[2] * QSC); t[3] = (__bf16)(a[3] * QSC);
      t[4] = (__bf16)(c[0] * QSC); t[5] = (__bf16)(c[1] * QSC);
      t[6] = (__bf16)(c[2] * QSC); t[7] = (__bf16)(c[3] * QSC);
      qf[mt][kf] = t;
    }
  }

  const float* kb = kg + ((size_t)b * KLEN + (size_t)s * CHUNK) * DH;
  const float* vb = vg + ((size_t)b * KLEN + (size_t)s * CHUNK) * DH;
  const int* mrow = maskg + b * KLEN + s * CHUNK;

  f32x4 kreg[8], va[4], vbr[4];  // prefetch staging

  auto load_tile = [&](int t) {
    const float* kt = kb + ((size_t)t * KT) * DH;
#pragma unroll
    for (int it = 0; it < 8; ++it) {
      int f = it * 256 + tid;
      kreg[it] = *(const f32x4*)(kt + (size_t)(f >> 5) * DH + (f & 31) * 4);
    }
    const float* vt = vb + ((size_t)t * KT) * DH;
#pragma unroll
    for (int it = 0; it < 4; ++it) {
      int u = it * 256 + tid;
      int m = u & 31;
      int dc = (u >> 5) * 4;
      va[it]  = *(const f32x4*)(vt + (size_t)(2 * m) * DH + dc);
      vbr[it] = *(const f32x4*)(vt + (size_t)(2 * m + 1) * DH + dc);
    }
  };

  auto store_tile = [&]() {
#pragma unroll
    for (int it = 0; it < 8; ++it) {
      int f = it * 256 + tid;
      bf16x4 w;
      w[0] = (__bf16)kreg[it][0]; w[1] = (__bf16)kreg[it][1];
      w[2] = (__bf16)kreg[it][2]; w[3] = (__bf16)kreg[it][3];
      *(bf16x4*)&sK[f >> 5][(f & 31) * 4] = w;
    }
#pragma unroll
    for (int it = 0; it < 4; ++it) {
      int u = it * 256 + tid;
      int m = u & 31;
      int dc = (u >> 5) * 4;
#pragma unroll
      for (int j = 0; j < 4; ++j) {
        bf16x2 p2;
        p2[0] = (__bf16)va[it][j];
        p2[1] = (__bf16)vbr[it][j];
        *(bf16x2*)&sVT[dc + j][2 * m] = p2;
      }
    }
  };

  f32x4 oacc[2][8];
#pragma unroll
  for (int mt = 0; mt < 2; ++mt)
#pragma unroll
    for (int i = 0; i < 8; ++i) oacc[mt][i] = (f32x4){0.f, 0.f, 0.f, 0.f};
  float mi[2][4], li[2][4];
#pragma unroll
  for (int mt = 0; mt < 2; ++mt)
#pragma unroll
    for (int r = 0; r < 4; ++r) { mi[mt][r] = -INFINITY; li[mt][r] = 0.f; }

  load_tile(0);
  store_tile();
  __syncthreads();

  for (int t = 0; t < NT; ++t) {
    const bool more = (t + 1 < NT);
    if (more) load_tile(t + 1);

    // ---- S = (Q*QSC) K^T : 2 m-tiles x 4 col-tiles x 4 k-steps ----
    f32x4 sa[2][4];
#pragma unroll
    for (int mt = 0; mt < 2; ++mt)
#pragma unroll
      for (int f = 0; f < 4; ++f) sa[mt][f] = (f32x4){0.f, 0.f, 0.f, 0.f};
#pragma unroll
    for (int kf = 0; kf < 4; ++kf) {
#pragma unroll
      for (int f = 0; f < 4; ++f) {
        bf16x8 bk = *(const bf16x8*)&sK[f * 16 + lc][kf * 32 + qd * 8];
        sa[0][f] = __builtin_amdgcn_mfma_f32_16x16x32_bf16(qf[0][kf], bk, sa[0][f], 0, 0, 0);
        sa[1][f] = __builtin_amdgcn_mfma_f32_16x16x32_bf16(qf[1][kf], bk, sa[1][f], 0, 0, 0);
      }
    }

    // ---- key-padding mask ----
    const int kv0 = t * KT;
#pragma unroll
    for (int f = 0; f < 4; ++f) {
      const bool keep = mrow[kv0 + f * 16 + lc] != 0;
#pragma unroll
      for (int mt = 0; mt < 2; ++mt)
#pragma unroll
        for (int r = 0; r < 4; ++r) sa[mt][f][r] = keep ? sa[mt][f][r] : NEGV;
    }

    // ---- online softmax per m-tile (rows: qd*4+r) ----
#pragma unroll
    for (int mt = 0; mt < 2; ++mt) {
      float rm[4], alpha[4], rs[4];
#pragma unroll
      for (int r = 0; r < 4; ++r)
        rm[r] = fmaxf(fmaxf(sa[mt][0][r], sa[mt][1][r]),
                      fmaxf(sa[mt][2][r], sa[mt][3][r]));
#pragma unroll
      for (int sh = 0; sh < 4; ++sh) {
        const int off = 1 << sh;
#pragma unroll
        for (int r = 0; r < 4; ++r)
          rm[r] = fmaxf(rm[r], __shfl_xor(rm[r], off, 64));
      }
#pragma unroll
      for (int r = 0; r < 4; ++r) {
        float mn = fmaxf(mi[mt][r], rm[r]);
        alpha[r] = __builtin_amdgcn_exp2f(mi[mt][r] - mn);
        mi[mt][r] = mn;
        rs[r] = 0.f;
      }
#pragma unroll
      for (int f = 0; f < 4; ++f) {
#pragma unroll
        for (int r = 0; r < 4; ++r) {
          float p = __builtin_amdgcn_exp2f(sa[mt][f][r] - mi[mt][r]);
          sa[mt][f][r] = p;
          rs[r] += p;
        }
      }
#pragma unroll
      for (int sh = 0; sh < 4; ++sh) {
        const int off = 1 << sh;
#pragma unroll
        for (int r = 0; r < 4; ++r) rs[r] += __shfl_xor(rs[r], off, 64);
      }
#pragma unroll
      for (int r = 0; r < 4; ++r) li[mt][r] = li[mt][r] * alpha[r] + rs[r];

      // P: C-layout -> LDS; rescale O
#pragma unroll
      for (int f = 0; f < 4; ++f)
#pragma unroll
        for (int r = 0; r < 4; ++r)
          sP[wv][mt * 16 + qd * 4 + r][f * 16 + lc] = (__bf16)sa[mt][f][r];
#pragma unroll
      for (int nt = 0; nt < 8; ++nt)
#pragma unroll
        for (int r = 0; r < 4; ++r) oacc[mt][nt][r] *= alpha[r];
    }

    // ---- O += P V : 2 k-steps x 8 d-tiles x 2 m-tiles ----
#pragma unroll
    for (int kp = 0; kp < 2; ++kp) {
      bf16x8 ap0 = *(const bf16x8*)&sP[wv][lc][kp * 32 + qd * 8];
      bf16x8 ap1 = *(const bf16x8*)&sP[wv][16 + lc][kp * 32 + qd * 8];
#pragma unroll
      for (int nt = 0; nt < 8; ++nt) {
        bf16x8 bv = *(const bf16x8*)&sVT[nt * 16 + lc][kp * 32 + qd * 8];
        oacc[0][nt] = __builtin_amdgcn_mfma_f32_16x16x32_bf16(ap0, bv, oacc[0][nt], 0, 0, 0);
        oacc[1][nt] = __builtin_amdgcn_mfma_f32_16x16x32_bf16(ap1, bv, oacc[1][nt], 0, 0, 0);
      }
    }

    __syncthreads();
    if (more) store_tile();
    __syncthreads();
  }

  // ---- epilogue: unnormalized partials + (m, l) per row ----
#pragma unroll
  for (int mt = 0; mt < 2; ++mt) {
    const int row0 = b * QL + qbase + mt * 16;
#pragma unroll
    for (int nt = 0; nt < 8; ++nt)
#pragma unroll
      for (int r = 0; r < 4; ++r) {
        size_t row = (size_t)s * TOTROWS + row0 + qd * 4 + r;
        opart[row * DH + nt * 16 + lc] = oacc[mt][nt][r];
      }
    if (lc == 0) {
#pragma unroll
      for (int r = 0; r < 4; ++r) {
        size_t row = (size_t)s * TOTROWS + row0 + qd * 4 + r;
        mlout[row * 2]     = mi[mt][r];
        mlout[row * 2 + 1] = li[mt][r];
      }
    }
  }
}

// ---------------------------------------------------------------------------
// Merge: combine S partials per row.  O = sum_s w_s O'_s / sum_s w_s l_s,
// w_s = exp2(m_s - M).  256 thr = 2 rows x 128 d.
// ---------------------------------------------------------------------------
__global__ void fattn_merge(const float* __restrict__ opart,
                            const float* __restrict__ ml,
                            float* __restrict__ outg, int S) {
  const int row = blockIdx.x * 2 + (threadIdx.x >> 7);
  const int d = threadIdx.x & 127;
  float ms[4], ls[4];
  float M = -INFINITY;
  for (int s = 0; s < S; ++s) {
    ms[s] = ml[((size_t)s * TOTROWS + row) * 2];
    ls[s] = ml[((size_t)s * TOTROWS + row) * 2 + 1];
    M = fmaxf(M, ms[s]);
  }
  float L = 0.f, acc = 0.f;
  for (int s = 0; s < S; ++s) {
    float w = __builtin_amdgcn_exp2f(ms[s] - M);
    L += w * ls[s];
    acc += w * opart[((size_t)s * TOTROWS + row) * DH + d];
  }
  outg[(size_t)row * DH + d] = acc / L;
}

// ---------------------------------------------------------------------------
// Legacy single-pass kernel (R2, proven) — fallback when ws is too small.
// ---------------------------------------------------------------------------
__global__ __launch_bounds__(256, 1) void fattn_mono(
    const float* __restrict__ qg, const float* __restrict__ kg,
    const float* __restrict__ vg, const int* __restrict__ maskg,
    float* __restrict__ outg) {
  __shared__ __bf16 sK[KT][KPITCH];
  __shared__ __bf16 sVT[DH][VPITCH];
  __shared__ __bf16 sP[4][16][PPITCH];

  const int tid = threadIdx.x;
  const int wv = tid >> 6;
  const int ln = tid & 63;
  const int qd = ln >> 4;
  const int lc = ln & 15;
  const int bid = blockIdx.x;
  const int b = bid >> 5;
  const int q0 = (bid & 31) << 6;
  const int qw = q0 + (wv << 4);

  bf16x8 qf[4];
  {
    const float* qr = qg + ((size_t)(b * QL + qw + lc)) * DH + qd * 8;
#pragma unroll
    for (int kf = 0; kf < 4; ++kf) {
      f32x4 a = *(const f32x4*)(qr + kf * 32);
      f32x4 c = *(const f32x4*)(qr + kf * 32 + 4);
      bf16x8 t;
      t[0] = (__bf16)(a[0] * QSC); t[1] = (__bf16)(a[1] * QSC);
      t[2] = (__bf16)(a[2] * QSC); t[3] = (__bf16)(a[3] * QSC);
      t[4] = (__bf16)(c[0] * QSC); t[5] = (__bf16)(c[1] * QSC);
      t[6] = (__bf16)(c[2] * QSC); t[7] = (__bf16)(c[3] * QSC);
      qf[kf] = t;
    }
  }

  const float* kb = kg + (size_t)b * KLEN * DH;
  const float* vb = vg + (size_t)b * KLEN * DH;
  const int* mrow = maskg + b * KLEN;

  f32x4 kreg[8], va[4], vbr[4];

  auto load_tile = [&](int t) {
    const float* kt = kb + ((size_t)t * KT) * DH;
#pragma unroll
    for (int it = 0; it < 8; ++it) {
      int f = it * 256 + tid;
      kreg[it] = *(const f32x4*)(kt + (size_t)(f >> 5) * DH + (f & 31) * 4);
    }
    const float* vt = vb + ((size_t)t * KT) * DH;
#pragma unroll
    for (int it = 0; it < 4; ++it) {
      int u = it * 256 + tid;
      int m = u & 31;
      int dc = (u >> 5) * 4;
      va[it]  = *(const f32x4*)(vt + (size_t)(2 * m) * DH + dc);
      vbr[it] = *(const f32x4*)(vt + (size_t)(2 * m + 1) * DH + dc);
    }
  };

  auto store_tile = [&]() {
#pragma unroll
    for (int it = 0; it < 8; ++it) {
      int f = it * 256 + tid;
      bf16x4 w;
      w[0] = (__bf16)kreg[it][0]; w[1] = (__bf16)kreg[it][1];
      w[2] = (__bf16)kreg[it][2]; w[3] = (__bf16)kreg[it][3];
      *(bf16x4*)&sK[f >> 5][(f & 31) * 4] = w;
    }
#pragma unroll
    for (int it = 0; it < 4; ++it) {
      int u = it * 256 + tid;
      int m = u & 31;
      int dc = (u >> 5) * 4;
#pragma unroll
      for (int j = 0; j < 4; ++j) {
        bf16x2 p2;
        p2[0] = (__bf16)va[it][j];
        p2[1] = (__bf16)vbr[it][j];
        *(bf16x2*)&sVT[dc + j][2 * m] = p2;
      }
    }
  };

  f32x4 oacc[8];
#pragma unroll
  for (int i = 0; i < 8; ++i) oacc[i] = (f32x4){0.f, 0.f, 0.f, 0.f};
  float mi[4] = {-INFINITY, -INFINITY, -INFINITY, -INFINITY};
  float li[4] = {0.f, 0.f, 0.f, 0.f};

  load_tile(0);
  store_tile();
  __syncthreads();

  for (int t = 0; t < (KLEN / KT); ++t) {
    const bool more = (t + 1 < (KLEN / KT));
    if (more) load_tile(t + 1);

    f32x4 sa[4];
#pragma unroll
    for (int f = 0; f < 4; ++f) sa[f] = (f32x4){0.f, 0.f, 0.f, 0.f};
#pragma unroll
    for (int kf = 0; kf < 4; ++kf) {
#pragma unroll
      for (int f = 0; f < 4; ++f) {
        bf16x8 bk = *(const bf16x8*)&sK[f * 16 + lc][kf * 32 + qd * 8];
        sa[f] = __builtin_amdgcn_mfma_f32_16x16x32_bf16(qf[kf], bk, sa[f], 0, 0, 0);
      }
    }

    const int kv0 = t * KT;
#pragma unroll
    for (int f = 0; f < 4; ++f) {
      const bool keep = mrow[kv0 + f * 16 + lc] != 0;
#pragma unroll
      for (int r = 0; r < 4; ++r) sa[f][r] = keep ? sa[f][r] : NEGV;
    }

    float rm[4], alpha[4], rs[4];
#pragma unroll
    for (int r = 0; r < 4; ++r)
      rm[r] = fmaxf(fmaxf(sa[0][r], sa[1][r]), fmaxf(sa[2][r], sa[3][r]));
#pragma unroll
    for (int sh = 0; sh < 4; ++sh) {
      const int off = 1 << sh;
#pragma unroll
      for (int r = 0; r < 4; ++r)
        rm[r] = fmaxf(rm[r], __shfl_xor(rm[r], off, 64));
    }
#pragma unroll
    for (int r = 0; r < 4; ++r) {
      float mn = fmaxf(mi[r], rm[r]);
      alpha[r] = __builtin_amdgcn_exp2f(mi[r] - mn);
      mi[r] = mn;
      rs[r] = 0.f;
    }
#pragma unroll
    for (int f = 0; f < 4; ++f) {
#pragma unroll
      for (int r = 0; r < 4; ++r) {
        float p = __builtin_amdgcn_exp2f(sa[f][r] - mi[r]);
        sa[f][r] = p;
        rs[r] += p;
      }
    }
#pragma unroll
    for (int sh = 0; sh < 4; ++sh) {
      const int off = 1 << sh;
#pragma unroll
      for (int r = 0; r < 4; ++r) rs[r] += __shfl_xor(rs[r], off, 64);
    }
#pragma unroll
    for (int r = 0; r < 4; ++r) li[r] = li[r] * alpha[r] + rs[r];

#pragma unroll
    for (int f = 0; f < 4; ++f)
#pragma unroll
      for (int r = 0; r < 4; ++r)
        sP[wv][qd * 4 + r][f * 16 + lc] = (__bf16)sa[f][r];
#pragma unroll
    for (int nt = 0; nt < 8; ++nt)
#pragma unroll
      for (int r = 0; r < 4; ++r) oacc[nt][r] *= alpha[r];

#pragma unroll
    for (int kp = 0; kp < 2; ++kp) {
      bf16x8 ap = *(const bf16x8*)&sP[wv][lc][kp * 32 + qd * 8];
#pragma unroll
      for (int nt = 0; nt < 8; ++nt) {
        bf16x8 bv = *(const bf16x8*)&sVT[nt * 16 + lc][kp * 32 + qd * 8];
        oacc[nt] = __builtin_amdgcn_mfma_f32_16x16x32_bf16(ap, bv, oacc[nt], 0, 0, 0);
      }
    }

    __syncthreads();
    if (more) store_tile();
    __syncthreads();
  }

  float inv[4];
#pragma unroll
  for (int r = 0; r < 4; ++r) inv[r] = 1.0f / li[r];
  float* orow = outg + ((size_t)(b * QL + qw)) * DH;
#pragma unroll
  for (int nt = 0; nt < 8; ++nt)
#pragma unroll
    for (int r = 0; r < 4; ++r)
      orow[(size_t)(qd * 4 + r) * DH + nt * 16 + lc] = oacc[nt][r] * inv[r];
}

extern "C" void kernel_launch(void* const* d_in, const int* in_sizes, int n_in,
                              void* d_out, int out_size, void* d_ws, size_t ws_size,
                              hipStream_t stream) {
  (void)in_sizes; (void)n_in; (void)out_size;
  const float* q = (const float*)d_in[0];
  const float* k = (const float*)d_in[1];
  const float* v = (const float*)d_in[2];
  const int* mask = (const int*)d_in[3];
  float* out = (float*)d_out;

  const size_t need4 = (size_t)4 * TOTROWS * DH * 4 + (size_t)4 * TOTROWS * 2 * 4;
  const size_t need2 = need4 / 2;

  int S = 0;
  if (ws_size >= need4) S = 4;
  else if (ws_size >= need2) S = 2;

  if (S > 0) {
    float* opart = (float*)d_ws;
    float* ml = opart + (size_t)S * TOTROWS * DH;
    fattn_split<<<dim3(BZ * 16 * S), dim3(256), 0, stream>>>(q, k, v, mask, opart, ml, S);
    fattn_merge<<<dim3(TOTROWS / 2), dim3(256), 0, stream>>>(opart, ml, out, S);
  } else {
    fattn_mono<<<dim3(BZ * (QL / 64)), dim3(256), 0, stream>>>(q, k, v, mask, out);
  }
}

// Round 4
// 132.802 us; speedup vs baseline: 1.6651x; 1.6651x over previous
//
#include <hip/hip_runtime.h>
#include <hip/hip_bf16.h>

// Masked SDPA, flash-attention, transposed formulation (S^T = K*Q^T, O^T = V^T*P^T).
// Pre-pass converts K/V fp32 -> bf16 into d_ws in swizzled 16B-chunk order so the
// main kernel can stage tiles with global_load_lds dwordx4 (async DMA), double-
// buffered with ONE barrier per tile (the barrier's auto vmcnt-drain is the wait
// we need anyway). Softmax state is per-lane scalar; P reaches the PV MFMA via
// ds_bpermute (no LDS round-trip). 512 thr = 8 waves = 4 q-subtiles x 2 kv-halves.

#define BZ 8
#define QL 2048
#define KLEN 2048
#define DH 128
#define KT 64
#define NTILES (KLEN / KT)  // 32
#define TCHUNKS 1024        // 16B chunks per 64-key tile (K: 16 kc x 64 key; V: 8 vc x 128 d)

typedef float f32x4 __attribute__((ext_vector_type(4)));
typedef int   i32x4 __attribute__((ext_vector_type(4)));
typedef __bf16 bf16x8 __attribute__((ext_vector_type(8)));
typedef __bf16 bf16x4 __attribute__((ext_vector_type(4)));
typedef __bf16 bf16x2 __attribute__((ext_vector_type(2)));

#define QSC 0.12751879523298232f  // SCALE * log2(e); softmax uses exp2
#define NEGV -1000000000.0f

__device__ __forceinline__ void gl2lds16(const void* g, void* l) {
  __builtin_amdgcn_global_load_lds((const __attribute__((address_space(1))) void*)g,
                                   (__attribute__((address_space(3))) void*)l, 16, 0, 0);
}
__device__ __forceinline__ float bperm(int srclane4, float v) {
  return __int_as_float(__builtin_amdgcn_ds_bpermute(srclane4, __float_as_int(v)));
}

// ---------------------------------------------------------------------------
// Pre-pass: K-hat. chunk (kc=d/8, key) of tile t stored at kc*64 + (key ^ ((kc&3)<<2)).
// ---------------------------------------------------------------------------
__global__ void prep_k(const float* __restrict__ kg, __bf16* __restrict__ khat) {
  const int blk = blockIdx.x;            // b*32 + t
  const int tid = threadIdx.x;
  const float* src_base = kg + (size_t)blk * KT * DH;
  __bf16* dst_base = khat + (size_t)blk * TCHUNKS * 8;
#pragma unroll
  for (int i = 0; i < 4; ++i) {
    int c = i * 256 + tid;               // 0..1023
    int kc = c >> 6, key = c & 63;
    const float* s = src_base + (size_t)key * DH + kc * 8;
    f32x4 a = *(const f32x4*)s;
    f32x4 b = *(const f32x4*)(s + 4);
    bf16x8 w;
    w[0]=(__bf16)a[0]; w[1]=(__bf16)a[1]; w[2]=(__bf16)a[2]; w[3]=(__bf16)a[3];
    w[4]=(__bf16)b[0]; w[5]=(__bf16)b[1]; w[6]=(__bf16)b[2]; w[7]=(__bf16)b[3];
    int g16 = kc * 64 + (key ^ ((kc & 3) << 2));
    *(bf16x8*)(dst_base + (size_t)g16 * 8) = w;
  }
}

// ---------------------------------------------------------------------------
// Pre-pass: V-hat (transposed). chunk (vc=key/8, d) stored at vc*128 + (d ^ ((vc&3)<<2)).
// chunk data = V[key = t*64 + vc*8 + j][d], j=0..7.
// ---------------------------------------------------------------------------
__global__ void prep_v(const float* __restrict__ vg, __bf16* __restrict__ vhat) {
  const int blk = blockIdx.x;            // b*32 + t
  const int tid = threadIdx.x;
  const float* src_base = vg + (size_t)blk * KT * DH;
  __bf16* dst_base = vhat + (size_t)blk * TCHUNKS * 8;
#pragma unroll
  for (int i = 0; i < 4; ++i) {
    int c = i * 256 + tid;               // 0..1023
    int vc = c >> 7, d = c & 127;
    bf16x8 w;
#pragma unroll
    for (int j = 0; j < 8; ++j)
      w[j] = (__bf16)src_base[(size_t)(vc * 8 + j) * DH + d];
    int g16 = vc * 128 + (d ^ ((vc & 3) << 2));
    *(bf16x8*)(dst_base + (size_t)g16 * 8) = w;
  }
}

// ---------------------------------------------------------------------------
// Main kernel. Grid 256 (b = bid&7 for XCD-L2 locality, qt = bid>>3), 512 thr.
// Wave wv: wq = wv&3 (q-subtile of 16 rows), h = wv>>2 (kv-half of 32 keys/tile).
// ---------------------------------------------------------------------------
__global__ __launch_bounds__(512) void fattn2(
    const __bf16* __restrict__ khat, const __bf16* __restrict__ vhat,
    const float* __restrict__ qg, const int* __restrict__ maskg,
    float* __restrict__ outg) {
  __shared__ __align__(16) __bf16 smem[2][2][TCHUNKS * 8];  // [K/V][buf] 64 KiB

  const int tid = threadIdx.x;
  const int wv = tid >> 6, ln = tid & 63;
  const int qd = ln >> 4, lc = ln & 15;
  const int b = blockIdx.x & 7, qt = blockIdx.x >> 3;
  const int q0 = qt * 64, wq = wv & 3, h = wv >> 2;

  // Q fragment (B-operand for S^T): lane holds Q[q0+wq*16+lc][kf*32+qd*8+j]*QSC
  bf16x8 qf[4];
  {
    const float* qr = qg + ((size_t)(b * QL + q0 + wq * 16 + lc)) * DH + qd * 8;
#pragma unroll
    for (int kf = 0; kf < 4; ++kf) {
      f32x4 a = *(const f32x4*)(qr + kf * 32);
      f32x4 c = *(const f32x4*)(qr + kf * 32 + 4);
      bf16x8 t;
      t[0]=(__bf16)(a[0]*QSC); t[1]=(__bf16)(a[1]*QSC); t[2]=(__bf16)(a[2]*QSC); t[3]=(__bf16)(a[3]*QSC);
      t[4]=(__bf16)(c[0]*QSC); t[5]=(__bf16)(c[1]*QSC); t[6]=(__bf16)(c[2]*QSC); t[7]=(__bf16)(c[3]*QSC);
      qf[kf] = t;
    }
  }

  const __bf16* Kb = khat + (size_t)b * NTILES * TCHUNKS * 8;
  const __bf16* Vb = vhat + (size_t)b * NTILES * TCHUNKS * 8;
  const int* mrow = maskg + b * KLEN;

  // async stage of tile t into buffer buf: 8 waves x 2 instr x 64 lanes = 1024 chunks
  auto stage = [&](int t, int buf) {
    const __bf16* kt = Kb + (size_t)t * TCHUNKS * 8;
    const __bf16* vt = Vb + (size_t)t * TCHUNKS * 8;
    const int c0 = (wv * 2) * 64;        // wave-uniform chunk base, lane adds ln*16B
    const int c1 = (wv * 2 + 1) * 64;
    gl2lds16(kt + (size_t)(c0 + ln) * 8, &smem[0][buf][c0 * 8]);
    gl2lds16(kt + (size_t)(c1 + ln) * 8, &smem[0][buf][c1 * 8]);
    gl2lds16(vt + (size_t)(c0 + ln) * 8, &smem[1][buf][c0 * 8]);
    gl2lds16(vt + (size_t)(c1 + ln) * 8, &smem[1][buf][c1 * 8]);
  };

  f32x4 oacc[8];
#pragma unroll
  for (int i = 0; i < 8; ++i) oacc[i] = (f32x4){0.f, 0.f, 0.f, 0.f};
  float mi = -INFINITY, li = 0.f;        // per-lane scalars (q-row = lc)

  // prologue: stage tile 0, load mask(0)
  stage(0, 0);
  i32x4 mc0 = *(const i32x4*)&mrow[h * 32 + qd * 4];
  i32x4 mc1 = *(const i32x4*)&mrow[h * 32 + 16 + qd * 4];
  i32x4 mn0 = {}, mn1 = {};

  for (int t = 0; t < NTILES; ++t) {
    __syncthreads();                     // drains stage(t)/mask(t); syncs buffers
    const bool more = (t + 1 < NTILES);
    if (more) {
      mn0 = *(const i32x4*)&mrow[(t + 1) * KT + h * 32 + qd * 4];
      mn1 = *(const i32x4*)&mrow[(t + 1) * KT + h * 32 + 16 + qd * 4];
      stage(t + 1, (t + 1) & 1);         // flies across the whole compute below
    }

    const __bf16* cK = smem[0][t & 1];
    const __bf16* cV = smem[1][t & 1];

    // ---- S^T = K * (Q*QSC)^T : 2 key-frags (f = h*2, h*2+1), 4 k-steps ----
    f32x4 sa0 = (f32x4){0.f, 0.f, 0.f, 0.f};
    f32x4 sa1 = (f32x4){0.f, 0.f, 0.f, 0.f};
    const int sw = qd << 2;
#pragma unroll
    for (int kf = 0; kf < 4; ++kf) {
      const int kc = kf * 4 + qd;
      bf16x8 k0 = *(const bf16x8*)&cK[(kc * 64 + (((h * 2) * 16 + lc) ^ sw)) * 8];
      bf16x8 k1 = *(const bf16x8*)&cK[(kc * 64 + (((h * 2 + 1) * 16 + lc) ^ sw)) * 8];
      sa0 = __builtin_amdgcn_mfma_f32_16x16x32_bf16(k0, qf[kf], sa0, 0, 0, 0);
      sa1 = __builtin_amdgcn_mfma_f32_16x16x32_bf16(k1, qf[kf], sa1, 0, 0, 0);
    }

    // ---- key-padding mask (C rows = keys = qd*4+r) ----
#pragma unroll
    for (int r = 0; r < 4; ++r) {
      sa0[r] = mc0[r] ? sa0[r] : NEGV;
      sa1[r] = mc1[r] ? sa1[r] : NEGV;
    }

    // ---- online softmax: per-lane scalar state for q-row lc ----
    float rm = sa0[0];
#pragma unroll
    for (int r = 1; r < 4; ++r) rm = fmaxf(rm, sa0[r]);
#pragma unroll
    for (int r = 0; r < 4; ++r) rm = fmaxf(rm, sa1[r]);
    rm = fmaxf(rm, __shfl_xor(rm, 16, 64));
    rm = fmaxf(rm, __shfl_xor(rm, 32, 64));
    const float mn = fmaxf(mi, rm);
    const float alpha = __builtin_amdgcn_exp2f(mi - mn);
    mi = mn;
    float rs = 0.f;
#pragma unroll
    for (int r = 0; r < 4; ++r) {
      sa0[r] = __builtin_amdgcn_exp2f(sa0[r] - mn); rs += sa0[r];
      sa1[r] = __builtin_amdgcn_exp2f(sa1[r] - mn); rs += sa1[r];
    }
    rs += __shfl_xor(rs, 16, 64);
    rs += __shfl_xor(rs, 32, 64);
    li = li * alpha + rs;

    // ---- P^T C-layout -> B-layout via ds_bpermute (no LDS round-trip) ----
    // B elem j (key = qd*8+j): frag = qd>>1, src lane = ((qd&1)*2 + (j>>2))*16 + lc, reg = j&3
    const int a0 = ((((qd & 1) * 2) * 16) + lc) * 4;
    const int a1 = a0 + 64;
    float tv[8];
#pragma unroll
    for (int r = 0; r < 4; ++r) {
      float x00 = bperm(a0, sa0[r]), x10 = bperm(a0, sa1[r]);
      float x01 = bperm(a1, sa0[r]), x11 = bperm(a1, sa1[r]);
      tv[r]     = (qd < 2) ? x00 : x10;
      tv[4 + r] = (qd < 2) ? x01 : x11;
    }
    bf16x8 pf;
#pragma unroll
    for (int j = 0; j < 8; ++j) pf[j] = (__bf16)tv[j];

    // ---- O^T rescale + O^T += V^T * P^T ----
#pragma unroll
    for (int nt = 0; nt < 8; ++nt)
#pragma unroll
      for (int r = 0; r < 4; ++r) oacc[nt][r] *= alpha;
    const int vcc = h * 4 + qd;
#pragma unroll
    for (int nt = 0; nt < 8; ++nt) {
      bf16x8 vf = *(const bf16x8*)&cV[(vcc * 128 + ((nt * 16 + lc) ^ sw)) * 8];
      oacc[nt] = __builtin_amdgcn_mfma_f32_16x16x32_bf16(vf, pf, oacc[nt], 0, 0, 0);
    }

    if (more) { mc0 = mn0; mc1 = mn1; }
  }

  // ---- merge the two kv-halves (waves h=1 publish, h=0 combine+store) ----
  __syncthreads();
  float* fb = (float*)&smem[0][0][0];    // 64 KiB scratch; 2304 floats per wq
  if (h == 1) {
    float* mb = fb + wq * 2304;
#pragma unroll
    for (int nt = 0; nt < 8; ++nt)
      *(f32x4*)&mb[(nt * 64 + ln) * 4] = oacc[nt];
    mb[2048 + ln * 2] = mi;
    mb[2048 + ln * 2 + 1] = li;
  }
  __syncthreads();
  if (h == 0) {
    const float* pb = fb + wq * 2304;
    const float m2 = pb[2048 + ln * 2], l2 = pb[2048 + ln * 2 + 1];
    const float M = fmaxf(mi, m2);
    const float w1 = __builtin_amdgcn_exp2f(mi - M);
    const float w2 = __builtin_amdgcn_exp2f(m2 - M);
    const float invL = 1.0f / (w1 * li + w2 * l2);
    float* orow = outg + ((size_t)(b * QL + q0 + wq * 16 + lc)) * DH;
#pragma unroll
    for (int nt = 0; nt < 8; ++nt) {
      f32x4 o2 = *(const f32x4*)&pb[(nt * 64 + ln) * 4];
      f32x4 res;
#pragma unroll
      for (int r = 0; r < 4; ++r) res[r] = (w1 * oacc[nt][r] + w2 * o2[r]) * invL;
      *(f32x4*)&orow[nt * 16 + qd * 4] = res;
    }
  }
}

// ---------------------------------------------------------------------------
// Fallback single-pass kernel (R2, proven) — used only if ws is too small.
// ---------------------------------------------------------------------------
#define KPITCH 136
#define VPITCH 72
#define PPITCH 72

__global__ __launch_bounds__(256, 1) void fattn_mono(
    const float* __restrict__ qg, const float* __restrict__ kg,
    const float* __restrict__ vg, const int* __restrict__ maskg,
    float* __restrict__ outg) {
  __shared__ __bf16 sK[KT][KPITCH];
  __shared__ __bf16 sVT[DH][VPITCH];
  __shared__ __bf16 sP[4][16][PPITCH];

  const int tid = threadIdx.x;
  const int wv = tid >> 6;
  const int ln = tid & 63;
  const int qd = ln >> 4;
  const int lc = ln & 15;
  const int bid = blockIdx.x;
  const int b = bid >> 5;
  const int q0 = (bid & 31) << 6;
  const int qw = q0 + (wv << 4);

  bf16x8 qf[4];
  {
    const float* qr = qg + ((size_t)(b * QL + qw + lc)) * DH + qd * 8;
#pragma unroll
    for (int kf = 0; kf < 4; ++kf) {
      f32x4 a = *(const f32x4*)(qr + kf * 32);
      f32x4 c = *(const f32x4*)(qr + kf * 32 + 4);
      bf16x8 t;
      t[0]=(__bf16)(a[0]*QSC); t[1]=(__bf16)(a[1]*QSC); t[2]=(__bf16)(a[2]*QSC); t[3]=(__bf16)(a[3]*QSC);
      t[4]=(__bf16)(c[0]*QSC); t[5]=(__bf16)(c[1]*QSC); t[6]=(__bf16)(c[2]*QSC); t[7]=(__bf16)(c[3]*QSC);
      qf[kf] = t;
    }
  }

  const float* kb = kg + (size_t)b * KLEN * DH;
  const float* vb = vg + (size_t)b * KLEN * DH;
  const int* mrow = maskg + b * KLEN;

  f32x4 kreg[8], va[4], vbr[4];

  auto load_tile = [&](int t) {
    const float* kt = kb + ((size_t)t * KT) * DH;
#pragma unroll
    for (int it = 0; it < 8; ++it) {
      int f = it * 256 + tid;
      kreg[it] = *(const f32x4*)(kt + (size_t)(f >> 5) * DH + (f & 31) * 4);
    }
    const float* vt = vb + ((size_t)t * KT) * DH;
#pragma unroll
    for (int it = 0; it < 4; ++it) {
      int u = it * 256 + tid;
      int m = u & 31;
      int dc = (u >> 5) * 4;
      va[it]  = *(const f32x4*)(vt + (size_t)(2 * m) * DH + dc);
      vbr[it] = *(const f32x4*)(vt + (size_t)(2 * m + 1) * DH + dc);
    }
  };

  auto store_tile = [&]() {
#pragma unroll
    for (int it = 0; it < 8; ++it) {
      int f = it * 256 + tid;
      bf16x4 w;
      w[0]=(__bf16)kreg[it][0]; w[1]=(__bf16)kreg[it][1];
      w[2]=(__bf16)kreg[it][2]; w[3]=(__bf16)kreg[it][3];
      *(bf16x4*)&sK[f >> 5][(f & 31) * 4] = w;
    }
#pragma unroll
    for (int it = 0; it < 4; ++it) {
      int u = it * 256 + tid;
      int m = u & 31;
      int dc = (u >> 5) * 4;
#pragma unroll
      for (int j = 0; j < 4; ++j) {
        bf16x2 p2;
        p2[0] = (__bf16)va[it][j];
        p2[1] = (__bf16)vbr[it][j];
        *(bf16x2*)&sVT[dc + j][2 * m] = p2;
      }
    }
  };

  f32x4 oacc[8];
#pragma unroll
  for (int i = 0; i < 8; ++i) oacc[i] = (f32x4){0.f, 0.f, 0.f, 0.f};
  float mi[4] = {-INFINITY, -INFINITY, -INFINITY, -INFINITY};
  float li[4] = {0.f, 0.f, 0.f, 0.f};

  load_tile(0);
  store_tile();
  __syncthreads();

  for (int t = 0; t < NTILES; ++t) {
    const bool more = (t + 1 < NTILES);
    if (more) load_tile(t + 1);

    f32x4 sa[4];
#pragma unroll
    for (int f = 0; f < 4; ++f) sa[f] = (f32x4){0.f, 0.f, 0.f, 0.f};
#pragma unroll
    for (int kf = 0; kf < 4; ++kf) {
#pragma unroll
      for (int f = 0; f < 4; ++f) {
        bf16x8 bk = *(const bf16x8*)&sK[f * 16 + lc][kf * 32 + qd * 8];
        sa[f] = __builtin_amdgcn_mfma_f32_16x16x32_bf16(qf[kf], bk, sa[f], 0, 0, 0);
      }
    }

    const int kv0 = t * KT;
#pragma unroll
    for (int f = 0; f < 4; ++f) {
      const bool keep = mrow[kv0 + f * 16 + lc] != 0;
#pragma unroll
      for (int r = 0; r < 4; ++r) sa[f][r] = keep ? sa[f][r] : NEGV;
    }

    float rm[4], alpha[4], rs[4];
#pragma unroll
    for (int r = 0; r < 4; ++r)
      rm[r] = fmaxf(fmaxf(sa[0][r], sa[1][r]), fmaxf(sa[2][r], sa[3][r]));
#pragma unroll
    for (int sh = 0; sh < 4; ++sh) {
      const int off = 1 << sh;
#pragma unroll
      for (int r = 0; r < 4; ++r)
        rm[r] = fmaxf(rm[r], __shfl_xor(rm[r], off, 64));
    }
#pragma unroll
    for (int r = 0; r < 4; ++r) {
      float mn = fmaxf(mi[r], rm[r]);
      alpha[r] = __builtin_amdgcn_exp2f(mi[r] - mn);
      mi[r] = mn;
      rs[r] = 0.f;
    }
#pragma unroll
    for (int f = 0; f < 4; ++f) {
#pragma unroll
      for (int r = 0; r < 4; ++r) {
        float p = __builtin_amdgcn_exp2f(sa[f][r] - mi[r]);
        sa[f][r] = p;
        rs[r] += p;
      }
    }
#pragma unroll
    for (int sh = 0; sh < 4; ++sh) {
      const int off = 1 << sh;
#pragma unroll
      for (int r = 0; r < 4; ++r) rs[r] += __shfl_xor(rs[r], off, 64);
    }
#pragma unroll
    for (int r = 0; r < 4; ++r) li[r] = li[r] * alpha[r] + rs[r];

#pragma unroll
    for (int f = 0; f < 4; ++f)
#pragma unroll
      for (int r = 0; r < 4; ++r)
        sP[wv][qd * 4 + r][f * 16 + lc] = (__bf16)sa[f][r];
#pragma unroll
    for (int nt = 0; nt < 8; ++nt)
#pragma unroll
      for (int r = 0; r < 4; ++r) oacc[nt][r] *= alpha[r];

#pragma unroll
    for (int kp = 0; kp < 2; ++kp) {
      bf16x8 ap = *(const bf16x8*)&sP[wv][lc][kp * 32 + qd * 8];
#pragma unroll
      for (int nt = 0; nt < 8; ++nt) {
        bf16x8 bv = *(const bf16x8*)&sVT[nt * 16 + lc][kp * 32 + qd * 8];
        oacc[nt] = __builtin_amdgcn_mfma_f32_16x16x32_bf16(ap, bv, oacc[nt], 0, 0, 0);
      }
    }

    __syncthreads();
    if (more) store_tile();
    __syncthreads();
  }

  float inv[4];
#pragma unroll
  for (int r = 0; r < 4; ++r) inv[r] = 1.0f / li[r];
  float* orow = outg + ((size_t)(b * QL + qw)) * DH;
#pragma unroll
  for (int nt = 0; nt < 8; ++nt)
#pragma unroll
    for (int r = 0; r < 4; ++r)
      orow[(size_t)(qd * 4 + r) * DH + nt * 16 + lc] = oacc[nt][r] * inv[r];
}

extern "C" void kernel_launch(void* const* d_in, const int* in_sizes, int n_in,
                              void* d_out, int out_size, void* d_ws, size_t ws_size,
                              hipStream_t stream) {
  (void)in_sizes; (void)n_in; (void)out_size;
  const float* q = (const float*)d_in[0];
  const float* k = (const float*)d_in[1];
  const float* v = (const float*)d_in[2];
  const int* mask = (const int*)d_in[3];
  float* out = (float*)d_out;

  const size_t kv_bytes = (size_t)BZ * KLEN * DH * sizeof(__bf16);  // 4 MiB each
  if (ws_size >= 2 * kv_bytes) {
    __bf16* khat = (__bf16*)d_ws;
    __bf16* vhat = khat + (size_t)BZ * KLEN * DH;
    prep_k<<<dim3(BZ * NTILES), dim3(256), 0, stream>>>(k, khat);
    prep_v<<<dim3(BZ * NTILES), dim3(256), 0, stream>>>(v, vhat);
    fattn2<<<dim3(BZ * (QL / 64)), dim3(512), 0, stream>>>(khat, vhat, q, mask, out);
  } else {
    fattn_mono<<<dim3(BZ * (QL / 64)), dim3(256), 0, stream>>>(q, k, v, mask, out);
  }
}